// Round 7
// baseline (463.738 us; speedup 1.0000x reference)
//
#include <hip/hip_runtime.h>
#include <hip/hip_bf16.h>
#include <math.h>

// =====================================================================
// GraphTransformerLayer, round 10
//   - ffn_fused: X@W1+b1 -> relu -> T kept in LDS -> T@W2+b2 + X resid
//     -> LN2 -> out, one kernel (eliminates Th write+read, 102 MB, and
//     one dispatch). Bs reused for W1-half / W2-K-slice alternately;
//     stride-130 LDS tiles, 65 KB total -> 2 blocks/CU.
//   - Xf fp32 intermediate removed: LN1 writes only bf16 Xh; LN2 resid
//     re-read from the As LDS tile (bf16, ~0.2% rel err on resid).
//     Eliminates another 102 MB.
//   - aggregate unchanged from r9 (control: 87 us @ 3.71 TB/s, the
//     confirmed byte-rate wall; FETCH 290 MB).
// =====================================================================

typedef __attribute__((ext_vector_type(8))) short bf16x8;
typedef __attribute__((ext_vector_type(4))) float f32x4;
typedef __attribute__((ext_vector_type(2))) _Float16 half2_t;

#define BSHIFT 9
#define BSIZE  512
#define KVROW  384

static __device__ __forceinline__ half2_t h2(unsigned u) {
    return __builtin_bit_cast(half2_t, u);
}
static __device__ __forceinline__ float bl(unsigned u) {
    return __uint_as_float(u << 16);
}
static __device__ __forceinline__ float bh(unsigned u) {
    return __uint_as_float(u & 0xffff0000u);
}

// ---------------- fused QKV GEMM ----------------
// Q -> f16 [N][128]; K -> fp8 e4m3 at KV+row*384; V -> bf16 at KV+row*384+128.
__global__ __launch_bounds__(256)
void qkv_fused(const float* __restrict__ h,
               const __hip_bfloat16* __restrict__ Wqt,
               const __hip_bfloat16* __restrict__ Wkt,
               const __hip_bfloat16* __restrict__ Wvt,
               unsigned short* __restrict__ Qh,
               unsigned char* __restrict__ KV,
               int N)
{
    __shared__ unsigned short As[64 * 136];
    __shared__ unsigned short Bs[128 * 136];

    const int tid  = threadIdx.x;
    const int row0 = blockIdx.x * 64;
    const int wave = tid >> 6, lane = tid & 63;
    const int quad = lane >> 4, l15 = lane & 15;

    #pragma unroll
    for (int it = 0; it < 4; ++it) {
        int i = tid + it * 256;
        int r = i >> 4, kb = i & 15;
        int rg = row0 + r; if (rg > N - 1) rg = N - 1;
        const float4 f0 = *(const float4*)&h[(size_t)rg * 128 + kb * 8];
        const float4 f1 = *(const float4*)&h[(size_t)rg * 128 + kb * 8 + 4];
        __hip_bfloat162 b01 = __float22bfloat162_rn(make_float2(f0.x, f0.y));
        __hip_bfloat162 b23 = __float22bfloat162_rn(make_float2(f0.z, f0.w));
        __hip_bfloat162 b45 = __float22bfloat162_rn(make_float2(f1.x, f1.y));
        __hip_bfloat162 b67 = __float22bfloat162_rn(make_float2(f1.z, f1.w));
        uint4 u;
        u.x = *(unsigned*)&b01; u.y = *(unsigned*)&b23;
        u.z = *(unsigned*)&b45; u.w = *(unsigned*)&b67;
        *(uint4*)&As[r * 136 + kb * 8] = u;
    }

    const __hip_bfloat16* Ws[3] = { Wqt, Wkt, Wvt };

    #pragma unroll
    for (int w = 0; w < 3; ++w) {
        #pragma unroll
        for (int it = 0; it < 8; ++it) {
            int i = tid + it * 256;
            int r = i >> 4, kb = i & 15;
            *(uint4*)&Bs[r * 136 + kb * 8] =
                *(const uint4*)&Ws[w][(size_t)r * 128 + kb * 8];
        }
        __syncthreads();

        f32x4 acc[8];
        #pragma unroll
        for (int t = 0; t < 8; ++t) acc[t] = (f32x4)0.f;

        const unsigned short* ap = &As[(wave * 16 + l15) * 136 + quad * 8];
        const unsigned short* bp = &Bs[l15 * 136 + quad * 8];
        #pragma unroll
        for (int ks = 0; ks < 4; ++ks) {
            bf16x8 a = *(const bf16x8*)(ap + ks * 32);
            #pragma unroll
            for (int t = 0; t < 8; ++t) {
                bf16x8 b = *(const bf16x8*)(bp + t * 16 * 136 + ks * 32);
                acc[t] = __builtin_amdgcn_mfma_f32_16x16x32_bf16(a, b, acc[t], 0, 0, 0);
            }
        }
        __syncthreads();

        const int rbase = row0 + wave * 16 + quad * 4;
        #pragma unroll
        for (int i = 0; i < 4; ++i) {
            int row = rbase + i;
            if (row >= N) continue;
            #pragma unroll
            for (int t = 0; t < 8; ++t) {
                float v = acc[t][i];
                if (w == 0) {
                    ((_Float16*)Qh)[(size_t)row * 128 + t * 16 + l15] = (_Float16)v;
                } else if (w == 1) {
                    int pk = __builtin_amdgcn_cvt_pk_fp8_f32(v, 0.f, 0, false);
                    KV[(size_t)row * KVROW + t * 16 + l15] = (unsigned char)(pk & 0xff);
                } else {
                    *(__hip_bfloat16*)(KV + (size_t)row * KVROW + 128 +
                                       (t * 16 + l15) * 2) = __float2bfloat16(v);
                }
            }
        }
    }
}

// ---------------- MFMA GEMM (bf16 A) ----------------
template<int K, int YLOOP, bool RELU, bool LN, bool RESID, bool BIAS>
__global__ __launch_bounds__(256)
void gemm_mfma(const __hip_bfloat16* __restrict__ Ab, int lda,
               const __hip_bfloat16* __restrict__ Bt, int ldbt,
               const float* __restrict__ bias, const float* __restrict__ resid,
               const float* __restrict__ lng, const float* __restrict__ lnb,
               float* __restrict__ Cf, __hip_bfloat16* __restrict__ Cb, int ldc,
               int N)
{
    constexpr int CK = 128;
    static_assert(YLOOP == 1 || K == CK, "YLOOP>1 needs single K chunk");
    __shared__ unsigned short As[64 * 136];
    __shared__ unsigned short Bs[128 * 136];

    const int tid  = threadIdx.x;
    const int row0 = blockIdx.x * 64;
    const int wave = tid >> 6, lane = tid & 63;
    const int quad = lane >> 4, l15 = lane & 15;
    const int rbase = row0 + wave * 16 + quad * 4;

    for (int yy = 0; yy < YLOOP; ++yy) {
        const int col0 = yy * 128;

        f32x4 acc[8];
        #pragma unroll
        for (int t = 0; t < 8; ++t) acc[t] = (f32x4)0.f;

        for (int kc = 0; kc < K; kc += CK) {
            if (yy == 0) {
                #pragma unroll
                for (int it = 0; it < 4; ++it) {          // A: 64 x 128
                    int i = tid + it * 256;
                    int r = i >> 4, kb = i & 15;
                    int rg = row0 + r; if (rg > N - 1) rg = N - 1;
                    *(uint4*)&As[r * 136 + kb * 8] =
                        *(const uint4*)&Ab[(size_t)rg * lda + kc + kb * 8];
                }
            }
            #pragma unroll
            for (int it = 0; it < 8; ++it) {              // Bt: 128 x 128
                int i = tid + it * 256;
                int r = i >> 4, kb = i & 15;
                *(uint4*)&Bs[r * 136 + kb * 8] =
                    *(const uint4*)&Bt[(size_t)(col0 + r) * ldbt + kc + kb * 8];
            }
            __syncthreads();
            const unsigned short* ap = &As[(wave * 16 + l15) * 136 + quad * 8];
            const unsigned short* bp = &Bs[l15 * 136 + quad * 8];
            #pragma unroll
            for (int ks = 0; ks < 4; ++ks) {
                bf16x8 a = *(const bf16x8*)(ap + ks * 32);
                #pragma unroll
                for (int t = 0; t < 8; ++t) {
                    bf16x8 b = *(const bf16x8*)(bp + t * 16 * 136 + ks * 32);
                    acc[t] = __builtin_amdgcn_mfma_f32_16x16x32_bf16(a, b, acc[t], 0, 0, 0);
                }
            }
            __syncthreads();
        }

        float vals[8][4];
        #pragma unroll
        for (int t = 0; t < 8; ++t) {
            float bv = BIAS ? bias[col0 + t * 16 + l15] : 0.f;
            #pragma unroll
            for (int i = 0; i < 4; ++i) vals[t][i] = acc[t][i] + bv;
        }
        if (RESID) {
            #pragma unroll
            for (int i = 0; i < 4; ++i) {
                int row = rbase + i;
                if (row < N) {
                    #pragma unroll
                    for (int t = 0; t < 8; ++t)
                        vals[t][i] += resid[(size_t)row * 128 + t * 16 + l15];
                }
            }
        }
        if (RELU) {
            #pragma unroll
            for (int t = 0; t < 8; ++t)
                #pragma unroll
                for (int i = 0; i < 4; ++i) vals[t][i] = fmaxf(vals[t][i], 0.f);
        }
        if (LN) {
            #pragma unroll
            for (int i = 0; i < 4; ++i) {
                float s = 0.f, sq = 0.f;
                #pragma unroll
                for (int t = 0; t < 8; ++t) { float v = vals[t][i]; s += v; sq += v * v; }
                s  += __shfl_xor(s, 1);  s  += __shfl_xor(s, 2);
                s  += __shfl_xor(s, 4);  s  += __shfl_xor(s, 8);
                sq += __shfl_xor(sq, 1); sq += __shfl_xor(sq, 2);
                sq += __shfl_xor(sq, 4); sq += __shfl_xor(sq, 8);
                float m  = s * (1.f / 128.f);
                float rs = rsqrtf(sq * (1.f / 128.f) - m * m + 1e-5f);
                #pragma unroll
                for (int t = 0; t < 8; ++t) {
                    float g = lng[t * 16 + l15], b = lnb[t * 16 + l15];
                    vals[t][i] = (vals[t][i] - m) * rs * g + b;
                }
            }
        }
        #pragma unroll
        for (int i = 0; i < 4; ++i) {
            int row = rbase + i;
            if (row >= N) continue;
            if (Cf) {
                #pragma unroll
                for (int t = 0; t < 8; ++t)
                    Cf[(size_t)row * ldc + col0 + t * 16 + l15] = vals[t][i];
            }
            if (Cb) {
                #pragma unroll
                for (int t = 0; t < 8; ++t)
                    Cb[(size_t)row * ldc + col0 + t * 16 + l15] =
                        __float2bfloat16(vals[t][i]);
            }
        }
    }
}

// ---------------- fused FFN + LN2 ----------------
// X (bf16) -> T = relu(X@W1+b1) in LDS -> Y = T@W2+b2 -> LN2(X + Y) -> out.
// Bs alternates W1 col-half and W2 K-slice; acc2 accumulates across halves.
__global__ __launch_bounds__(256)
void ffn_fused(const __hip_bfloat16* __restrict__ Xh,
               const __hip_bfloat16* __restrict__ W1t,   // [256][128]
               const __hip_bfloat16* __restrict__ W2t,   // [128][256]
               const float* __restrict__ b1, const float* __restrict__ b2,
               const float* __restrict__ lng, const float* __restrict__ lnb,
               float* __restrict__ out, int N)
{
    constexpr int SA = 130;
    __shared__ unsigned short As[64 * SA];
    __shared__ unsigned short Bs[128 * SA];
    __shared__ unsigned short Ts[64 * SA];

    const int tid  = threadIdx.x;
    const int row0 = blockIdx.x * 64;
    const int wave = tid >> 6, lane = tid & 63;
    const int quad = lane >> 4, l15 = lane & 15;
    const int rbase = row0 + wave * 16 + quad * 4;

    // stage A = X tile (64 x 128 bf16)
    #pragma unroll
    for (int it = 0; it < 4; ++it) {
        int i = tid + it * 256;
        int r = i >> 4, kb = i & 15;
        int rg = row0 + r; if (rg > N - 1) rg = N - 1;
        *(uint4*)&As[r * SA + kb * 8] =
            *(const uint4*)&Xh[(size_t)rg * 128 + kb * 8];
    }

    f32x4 acc2[8];
    #pragma unroll
    for (int t = 0; t < 8; ++t) acc2[t] = (f32x4)0.f;

    #pragma unroll
    for (int half = 0; half < 2; ++half) {
        // ---- stage Bs = W1t col-half [half*128 .. +128), K = 128 ----
        #pragma unroll
        for (int it = 0; it < 8; ++it) {
            int i = tid + it * 256;
            int r = i >> 4, kb = i & 15;
            *(uint4*)&Bs[r * SA + kb * 8] =
                *(const uint4*)&W1t[(size_t)(half * 128 + r) * 128 + kb * 8];
        }
        __syncthreads();

        f32x4 acc1[8];
        #pragma unroll
        for (int t = 0; t < 8; ++t) acc1[t] = (f32x4)0.f;
        {
            const unsigned short* ap = &As[(wave * 16 + l15) * SA + quad * 8];
            const unsigned short* bp = &Bs[l15 * SA + quad * 8];
            #pragma unroll
            for (int ks = 0; ks < 4; ++ks) {
                bf16x8 a = *(const bf16x8*)(ap + ks * 32);
                #pragma unroll
                for (int t = 0; t < 8; ++t) {
                    bf16x8 b = *(const bf16x8*)(bp + t * 16 * SA + ks * 32);
                    acc1[t] = __builtin_amdgcn_mfma_f32_16x16x32_bf16(a, b, acc1[t], 0, 0, 0);
                }
            }
        }
        __syncthreads();   // Bs consumed; Ts(prev half) consumed

        // ---- T = relu(acc1 + b1) -> Ts (bf16) ----
        #pragma unroll
        for (int t = 0; t < 8; ++t) {
            float bv = b1[half * 128 + t * 16 + l15];
            #pragma unroll
            for (int i = 0; i < 4; ++i) {
                float v = fmaxf(acc1[t][i] + bv, 0.f);
                __hip_bfloat16 hbv = __float2bfloat16(v);
                Ts[(wave * 16 + quad * 4 + i) * SA + t * 16 + l15] =
                    *(unsigned short*)&hbv;
            }
        }

        // ---- stage Bs = W2t K-slice [half*128 .. +128), 128 cols ----
        #pragma unroll
        for (int it = 0; it < 8; ++it) {
            int i = tid + it * 256;
            int r = i >> 4, kb = i & 15;
            *(uint4*)&Bs[r * SA + kb * 8] =
                *(const uint4*)&W2t[(size_t)r * 256 + half * 128 + kb * 8];
        }
        __syncthreads();   // Ts written + Bs(W2 slice) visible

        {
            const unsigned short* ap = &Ts[(wave * 16 + l15) * SA + quad * 8];
            const unsigned short* bp = &Bs[l15 * SA + quad * 8];
            #pragma unroll
            for (int ks = 0; ks < 4; ++ks) {
                bf16x8 a = *(const bf16x8*)(ap + ks * 32);
                #pragma unroll
                for (int t = 0; t < 8; ++t) {
                    bf16x8 b = *(const bf16x8*)(bp + t * 16 * SA + ks * 32);
                    acc2[t] = __builtin_amdgcn_mfma_f32_16x16x32_bf16(a, b, acc2[t], 0, 0, 0);
                }
            }
        }
        __syncthreads();   // before next half overwrites Bs/Ts
    }

    // ---- epilogue: vals = acc2 + b2 + X(resid from As) -> LN2 -> out ----
    float vals[8][4];
    #pragma unroll
    for (int t = 0; t < 8; ++t) {
        float bv = b2[t * 16 + l15];
        #pragma unroll
        for (int i = 0; i < 4; ++i) {
            float xr = __uint_as_float(
                (unsigned)As[(wave * 16 + quad * 4 + i) * SA + t * 16 + l15] << 16);
            vals[t][i] = acc2[t][i] + bv + xr;
        }
    }
    #pragma unroll
    for (int i = 0; i < 4; ++i) {
        float s = 0.f, sq = 0.f;
        #pragma unroll
        for (int t = 0; t < 8; ++t) { float v = vals[t][i]; s += v; sq += v * v; }
        s  += __shfl_xor(s, 1);  s  += __shfl_xor(s, 2);
        s  += __shfl_xor(s, 4);  s  += __shfl_xor(s, 8);
        sq += __shfl_xor(sq, 1); sq += __shfl_xor(sq, 2);
        sq += __shfl_xor(sq, 4); sq += __shfl_xor(sq, 8);
        float m  = s * (1.f / 128.f);
        float rs = rsqrtf(sq * (1.f / 128.f) - m * m + 1e-5f);
        #pragma unroll
        for (int t = 0; t < 8; ++t) {
            float g = lng[t * 16 + l15], b = lnb[t * 16 + l15];
            vals[t][i] = (vals[t][i] - m) * rs * g + b;
        }
    }
    #pragma unroll
    for (int i = 0; i < 4; ++i) {
        int row = rbase + i;
        if (row >= N) continue;
        #pragma unroll
        for (int t = 0; t < 8; ++t)
            out[(size_t)row * 128 + t * 16 + l15] = vals[t][i];
    }
}

// ---------------- weight cast+transpose (+ bCnt zero) ----------------
struct WArgs {
    const float* src[6];
    __hip_bfloat16* dst[6];
    int R[6], C[6];
};
__global__ __launch_bounds__(256)
void cast_w(WArgs wa, int* __restrict__ bCnt)
{
    if (blockIdx.x == 0 && blockIdx.y == 0) bCnt[threadIdx.x] = 0;
    int w = blockIdx.y;
    int R = wa.R[w], C = wa.C[w];
    int i = blockIdx.x * 256 + threadIdx.x;
    if (i >= R * C) return;
    int sh = (C == 256) ? 8 : 7;
    int r = i >> sh, c = i & (C - 1);
    wa.dst[w][(size_t)c * R + r] = __float2bfloat16(wa.src[w][i]);
}

// ---------------- two-level bucketed sort of edges by dst ----------------
__global__ __launch_bounds__(256)
void bucket_hist(const int* __restrict__ dst, int* __restrict__ bCnt,
                 int E, int chunk, int NB)
{
    __shared__ int bh[256];
    const int t = threadIdx.x;
    bh[t] = 0;
    __syncthreads();
    const int s0 = blockIdx.x * chunk;
    const int s1 = min(E, s0 + chunk);
    for (int i = s0 + t; i < s1; i += 256)
        atomicAdd(&bh[dst[i] >> BSHIFT], 1);
    __syncthreads();
    if (t < NB && bh[t]) atomicAdd(&bCnt[t], bh[t]);
}

__global__ __launch_bounds__(256)
void bucket_scan(const int* __restrict__ bCnt, int* __restrict__ bBase,
                 int* __restrict__ gCur, int* __restrict__ rowStart,
                 int N, int E, int NB)
{
    __shared__ int wsum[4];
    const int t = threadIdx.x, lane = t & 63, wv = t >> 6;
    int v = (t < NB) ? bCnt[t] : 0;
    const int s = v;
    for (int off = 1; off < 64; off <<= 1) {
        int u = __shfl_up(v, off);
        if (lane >= off) v += u;
    }
    if (lane == 63) wsum[wv] = v;
    __syncthreads();
    int add = 0;
    for (int w = 0; w < wv; ++w) add += wsum[w];
    const int excl = v + add - s;
    if (t <= NB) bBase[t] = excl;
    if (t < NB)  gCur[t]  = excl;
    if (t == 0)  rowStart[N] = E;
}

__global__ __launch_bounds__(256)
void partition_kernel(const int* __restrict__ src, const int* __restrict__ dst,
                      int* __restrict__ gCur, uint2* __restrict__ P,
                      int E, int chunk, int NB)
{
    __shared__ int ch[256];
    __shared__ int cur[256];
    const int t = threadIdx.x;
    ch[t] = 0;
    __syncthreads();
    const int s0 = blockIdx.x * chunk;
    const int s1 = min(E, s0 + chunk);
    for (int i = s0 + t; i < s1; i += 256)
        atomicAdd(&ch[dst[i] >> BSHIFT], 1);
    __syncthreads();
    if (t < NB) {
        int c = ch[t];
        cur[t] = c ? atomicAdd(&gCur[t], c) : 0;
    }
    __syncthreads();
    for (int i = s0 + t; i < s1; i += 256) {
        int d = dst[i];
        int pos = atomicAdd(&cur[d >> BSHIFT], 1);
        P[pos] = make_uint2((unsigned)src[i], (unsigned)d);
    }
}

__global__ __launch_bounds__(256)
void bucket_scatter(const uint2* __restrict__ P, const int* __restrict__ bBase,
                    int* __restrict__ rowStart, int* __restrict__ esrc, int N)
{
    __shared__ int hist[BSIZE];
    __shared__ int cur[BSIZE];
    __shared__ int wsum[4];

    const int b  = blockIdx.x;
    const int t  = threadIdx.x;
    const int d0 = b << BSHIFT;
    const int bb  = bBase[b];
    const int cnt = bBase[b + 1] - bb;

    hist[t] = 0; hist[t + 256] = 0;
    __syncthreads();
    for (int i = t; i < cnt; i += 256)
        atomicAdd(&hist[(int)P[bb + i].y - d0], 1);
    __syncthreads();

    {
        const int a0 = hist[2 * t], a1 = hist[2 * t + 1];
        int v = a0 + a1;
        const int s = v;
        const int lane = t & 63, wv = t >> 6;
        for (int off = 1; off < 64; off <<= 1) {
            int u = __shfl_up(v, off);
            if (lane >= off) v += u;
        }
        if (lane == 63) wsum[wv] = v;
        __syncthreads();
        int add = 0;
        for (int w = 0; w < wv; ++w) add += wsum[w];
        const int exclT = v + add - s;
        cur[2 * t]     = exclT;
        cur[2 * t + 1] = exclT + a0;
    }
    __syncthreads();
    for (int i = t; i < BSIZE; i += 256) {
        int d = d0 + i;
        if (d < N) rowStart[d] = bb + cur[i];
    }
    __syncthreads();
    for (int i = t; i < cnt; i += 256) {
        uint2 p = P[bb + i];
        int pos = atomicAdd(&cur[(int)p.y - d0], 1);
        esrc[bb + pos] = (int)p.x;
    }
}

// ---------------- aggregation ----------------
// wave = 4 dst-groups of 16 lanes; 8 edges per iteration (2 per group).
// KV row: 128 B fp8 K + 256 B bf16 V. K decoded via v_cvt_pk_f32_fp8.
__global__ __launch_bounds__(256)
void aggregate_kernel(unsigned short* __restrict__ Qp,
                      const unsigned char* __restrict__ KV,
                      const int* __restrict__ esrc,
                      const int* __restrict__ rowStart, int N)
{
    const int lane = threadIdx.x & 63;
    const int wid  = threadIdx.x >> 6;
    const int d    = blockIdx.x * 4 + wid;
    if (d >= N) return;

    const int c = lane & 15;      // chunk: elems [c*8, c*8+8), head = c>>1
    const int g = lane >> 4;      // edge slot 0..3

    const uint4 qraw = *(const uint4*)(Qp + (size_t)d * 128u + c * 8);
    const half2_t q0 = h2(qraw.x), q1 = h2(qraw.y),
                  q2 = h2(qraw.z), q3 = h2(qraw.w);
    const float qf0 = (float)q0.x, qf1 = (float)q0.y;
    const float qf2 = (float)q1.x, qf3 = (float)q1.y;
    const float qf4 = (float)q2.x, qf5 = (float)q2.y;
    const float qf6 = (float)q3.x, qf7 = (float)q3.y;

    const int beg = rowStart[d];
    const int end = rowStart[d + 1];
    const int endm1 = end - 1;

    float a0 = 0.f, a1 = 0.f, a2 = 0.f, a3 = 0.f;
    float a4 = 0.f, a5 = 0.f, a6 = 0.f, a7 = 0.f, z = 0.f;
    const float S = 0.36067376022224085f;  // 0.25 * log2(e)
    const float C = 7.2134752044448170f;   // 5 * log2(e)

    const int nIt = (end - beg + 7) >> 3;
    #pragma unroll 2
    for (int it = 0; it < nIt; ++it) {
        const int ea = beg + it * 8 + g;
        const int eb = ea + 4;
        const bool va = ea < end;
        const bool vb = eb < end;
        const int sa = esrc[va ? ea : endm1];
        const int sb = esrc[vb ? eb : endm1];
        const unsigned char* pa = KV + (size_t)(unsigned)sa * (size_t)KVROW;
        const unsigned char* pb = KV + (size_t)(unsigned)sb * (size_t)KVROW;
        const uint2 ka = *(const uint2*)(pa + c * 8);          // K fp8 x8
        const uint4 vra = *(const uint4*)(pa + 128 + c * 16);  // V bf16 x8
        const uint2 kb = *(const uint2*)(pb + c * 8);
        const uint4 vrb = *(const uint4*)(pb + 128 + c * 16);

        auto ka01 = __builtin_amdgcn_cvt_pk_f32_fp8(ka.x, false);
        auto ka23 = __builtin_amdgcn_cvt_pk_f32_fp8(ka.x, true);
        auto ka45 = __builtin_amdgcn_cvt_pk_f32_fp8(ka.y, false);
        auto ka67 = __builtin_amdgcn_cvt_pk_f32_fp8(ka.y, true);
        float p = ka01[0] * qf0 + ka01[1] * qf1 + ka23[0] * qf2 + ka23[1] * qf3
                + ka45[0] * qf4 + ka45[1] * qf5 + ka67[0] * qf6 + ka67[1] * qf7;
        p += __shfl_xor(p, 1);                       // head = 2 lanes
        float se = exp2f(fminf(C, fmaxf(-C, p * S)));
        se = va ? se : 0.f;

        auto kb01 = __builtin_amdgcn_cvt_pk_f32_fp8(kb.x, false);
        auto kb23 = __builtin_amdgcn_cvt_pk_f32_fp8(kb.x, true);
        auto kb45 = __builtin_amdgcn_cvt_pk_f32_fp8(kb.y, false);
        auto kb67 = __builtin_amdgcn_cvt_pk_f32_fp8(kb.y, true);
        float p2 = kb01[0] * qf0 + kb01[1] * qf1 + kb23[0] * qf2 + kb23[1] * qf3
                 + kb45[0] * qf4 + kb45[1] * qf5 + kb67[0] * qf6 + kb67[1] * qf7;
        p2 += __shfl_xor(p2, 1);
        float se2 = exp2f(fminf(C, fmaxf(-C, p2 * S)));
        se2 = vb ? se2 : 0.f;

        a0 += bl(vra.x) * se; a1 += bh(vra.x) * se;
        a2 += bl(vra.y) * se; a3 += bh(vra.y) * se;
        a4 += bl(vra.z) * se; a5 += bh(vra.z) * se;
        a6 += bl(vra.w) * se; a7 += bh(vra.w) * se;
        z  += se;

        a0 += bl(vrb.x) * se2; a1 += bh(vrb.x) * se2;
        a2 += bl(vrb.y) * se2; a3 += bh(vrb.y) * se2;
        a4 += bl(vrb.z) * se2; a5 += bh(vrb.z) * se2;
        a6 += bl(vrb.w) * se2; a7 += bh(vrb.w) * se2;
        z  += se2;
    }

    a0 += __shfl_xor(a0, 16); a1 += __shfl_xor(a1, 16);
    a2 += __shfl_xor(a2, 16); a3 += __shfl_xor(a3, 16);
    a4 += __shfl_xor(a4, 16); a5 += __shfl_xor(a5, 16);
    a6 += __shfl_xor(a6, 16); a7 += __shfl_xor(a7, 16);
    z  += __shfl_xor(z, 16);
    a0 += __shfl_xor(a0, 32); a1 += __shfl_xor(a1, 32);
    a2 += __shfl_xor(a2, 32); a3 += __shfl_xor(a3, 32);
    a4 += __shfl_xor(a4, 32); a5 += __shfl_xor(a5, 32);
    a6 += __shfl_xor(a6, 32); a7 += __shfl_xor(a7, 32);
    z  += __shfl_xor(z, 32);

    if (g == 0) {
        const float inv = 1.0f / (z + 1e-6f);
        __hip_bfloat162 p0 = __float22bfloat162_rn(make_float2(a0 * inv, a1 * inv));
        __hip_bfloat162 p1 = __float22bfloat162_rn(make_float2(a2 * inv, a3 * inv));
        __hip_bfloat162 p2 = __float22bfloat162_rn(make_float2(a4 * inv, a5 * inv));
        __hip_bfloat162 p3 = __float22bfloat162_rn(make_float2(a6 * inv, a7 * inv));
        uint4 o;
        o.x = *(unsigned*)&p0; o.y = *(unsigned*)&p1;
        o.z = *(unsigned*)&p2; o.w = *(unsigned*)&p3;
        *(uint4*)(Qp + (size_t)d * 128u + c * 8) = o;
    }
}

// =====================================================================
extern "C" void kernel_launch(void* const* d_in, const int* in_sizes, int n_in,
                              void* d_out, int out_size, void* d_ws, size_t ws_size,
                              hipStream_t stream)
{
    const float* h    = (const float*)d_in[0];
    const int*   src  = (const int*)  d_in[1];
    const int*   dst  = (const int*)  d_in[2];
    const float* Wq   = (const float*)d_in[3];
    const float* Wk   = (const float*)d_in[4];
    const float* Wv   = (const float*)d_in[5];
    const float* Wo   = (const float*)d_in[6];
    const float* bo   = (const float*)d_in[7];
    const float* ln1g = (const float*)d_in[8];
    const float* ln1b = (const float*)d_in[9];
    const float* W1   = (const float*)d_in[10];
    const float* b1   = (const float*)d_in[11];
    const float* W2   = (const float*)d_in[12];
    const float* b2   = (const float*)d_in[13];
    const float* ln2g = (const float*)d_in[14];
    const float* ln2b = (const float*)d_in[15];

    const int N = in_sizes[0] / 128;
    const int E = in_sizes[1];
    const int NB = (N + BSIZE - 1) >> BSHIFT;

    // ---- workspace layout ----
    unsigned short* Qh = (unsigned short*)d_ws;          // N*128 f16 (Q), bf16 h_attn after agg
    unsigned char*  KVc = (unsigned char*)(Qh + (size_t)N * 128);  // N*384 B: K fp8 | V bf16
    __hip_bfloat16* Xh = (__hip_bfloat16*)(KVc + (size_t)N * KVROW);  // N*128 bf16 (LN1 out)
    __hip_bfloat16* Wt = (__hip_bfloat16*)(Xh + (size_t)N * 128);
    __hip_bfloat16* Wqt = Wt;
    __hip_bfloat16* Wkt = Wqt + 16384;
    __hip_bfloat16* Wvt = Wkt + 16384;
    __hip_bfloat16* Wot = Wvt + 16384;
    __hip_bfloat16* W1t = Wot + 16384;        // [256][128]
    __hip_bfloat16* W2t = W1t + 32768;        // [128][256]
    int* ib       = (int*)(W2t + 32768);
    int* bCnt     = ib;                       // 256
    int* bBase    = ib + 256;                 // 257
    int* gCur     = ib + 514;                 // 256
    int* rowStart = ib + 770;                 // N+1
    int* esrc     = ib + 770 + N + 2;         // E
    uint2* P      = (uint2*)Xh;               // E pairs overlay Xh (dead during sort:
                                              //   Xh written only at LN1, after sort+agg)

    const dim3 blk(256);
    const int  nb    = (N + 63) / 64;
    const int  chunk = (E + 255) / 256;

    // ---- weight cast+transpose (+ bCnt zero) ----
    WArgs wa;
    wa.src[0] = Wq; wa.src[1] = Wk; wa.src[2] = Wv; wa.src[3] = Wo; wa.src[4] = W1; wa.src[5] = W2;
    wa.dst[0] = Wqt; wa.dst[1] = Wkt; wa.dst[2] = Wvt; wa.dst[3] = Wot; wa.dst[4] = W1t; wa.dst[5] = W2t;
    wa.R[0] = wa.R[1] = wa.R[2] = wa.R[3] = 128; wa.R[4] = 128; wa.R[5] = 256;
    wa.C[0] = wa.C[1] = wa.C[2] = wa.C[3] = 128; wa.C[4] = 256; wa.C[5] = 128;
    cast_w<<<dim3(128, 6), blk, 0, stream>>>(wa, bCnt);

    // ---- fused QKV (h read once) ----
    qkv_fused<<<dim3(nb), blk, 0, stream>>>(h, Wqt, Wkt, Wvt, Qh, KVc, N);

    // ---- bucketed sort of edges by dst ----
    bucket_hist<<<dim3(256), blk, 0, stream>>>(dst, bCnt, E, chunk, NB);
    bucket_scan<<<dim3(1), blk, 0, stream>>>(bCnt, bBase, gCur, rowStart, N, E, NB);
    partition_kernel<<<dim3(256), blk, 0, stream>>>(src, dst, gCur, P, E, chunk, NB);
    bucket_scatter<<<dim3(NB), blk, 0, stream>>>(P, bBase, rowStart, esrc, N);

    // ---- aggregate (reads f16 Q + fp8 K + bf16 V, writes bf16 h_attn into Qh) ----
    aggregate_kernel<<<dim3((N + 3) / 4), blk, 0, stream>>>(Qh, KVc, esrc, rowStart, N);

    // ---- X = LN1(h + h_attn@Wo + bo) -> bf16 Xh only ----
    gemm_mfma<128,1,false,true,true,true><<<dim3(nb), blk, 0, stream>>>(
        (const __hip_bfloat16*)Qh, 128, Wot, 128, bo, h, ln1g, ln1b,
        nullptr, Xh, 128, N);

    // ---- out = LN2(X + relu(X@W1+b1)@W2 + b2), T never leaves LDS ----
    ffn_fused<<<dim3(nb), blk, 0, stream>>>(
        Xh, W1t, W2t, b1, b2, ln2g, ln2b, (float*)d_out, N);
}

// Round 8
// 382.365 us; speedup vs baseline: 1.2128x; 1.2128x over previous
//
#include <hip/hip_runtime.h>
#include <hip/hip_bf16.h>
#include <math.h>

// =====================================================================
// GraphTransformerLayer, round 11
//   - REVERT r10's ffn_fused (137 us @ 18.6% occupancy: 66.5 KB LDS ->
//     2 blocks/CU, 6-barrier serial chain, nothing hides L2 restage
//     latency). Back to r9's separate W1/W2 GEMMs (27 KB LDS).
//   - KEEP r10's Xf-elimination (r10 proved bf16 resid: absmax identical
//     0.0859): LN1 writes only bf16 Xh; W2 reads LN2-resid from Xh via
//     new RB16 flag. Net -77 MB streaming traffic vs r9.
//   - P overlays Xh (dead during sort); Th overlays Qh+KV (dead after
//     LN1). aggregate unchanged (control: 87 us @ 3.71 TB/s wall).
// =====================================================================

typedef __attribute__((ext_vector_type(8))) short bf16x8;
typedef __attribute__((ext_vector_type(4))) float f32x4;
typedef __attribute__((ext_vector_type(2))) _Float16 half2_t;

#define BSHIFT 9
#define BSIZE  512
#define KVROW  384

static __device__ __forceinline__ half2_t h2(unsigned u) {
    return __builtin_bit_cast(half2_t, u);
}
static __device__ __forceinline__ float bl(unsigned u) {
    return __uint_as_float(u << 16);
}
static __device__ __forceinline__ float bh(unsigned u) {
    return __uint_as_float(u & 0xffff0000u);
}

// ---------------- fused QKV GEMM ----------------
// Q -> f16 [N][128]; K -> fp8 e4m3 at KV+row*384; V -> bf16 at KV+row*384+128.
__global__ __launch_bounds__(256)
void qkv_fused(const float* __restrict__ h,
               const __hip_bfloat16* __restrict__ Wqt,
               const __hip_bfloat16* __restrict__ Wkt,
               const __hip_bfloat16* __restrict__ Wvt,
               unsigned short* __restrict__ Qh,
               unsigned char* __restrict__ KV,
               int N)
{
    __shared__ unsigned short As[64 * 136];
    __shared__ unsigned short Bs[128 * 136];

    const int tid  = threadIdx.x;
    const int row0 = blockIdx.x * 64;
    const int wave = tid >> 6, lane = tid & 63;
    const int quad = lane >> 4, l15 = lane & 15;

    #pragma unroll
    for (int it = 0; it < 4; ++it) {
        int i = tid + it * 256;
        int r = i >> 4, kb = i & 15;
        int rg = row0 + r; if (rg > N - 1) rg = N - 1;
        const float4 f0 = *(const float4*)&h[(size_t)rg * 128 + kb * 8];
        const float4 f1 = *(const float4*)&h[(size_t)rg * 128 + kb * 8 + 4];
        __hip_bfloat162 b01 = __float22bfloat162_rn(make_float2(f0.x, f0.y));
        __hip_bfloat162 b23 = __float22bfloat162_rn(make_float2(f0.z, f0.w));
        __hip_bfloat162 b45 = __float22bfloat162_rn(make_float2(f1.x, f1.y));
        __hip_bfloat162 b67 = __float22bfloat162_rn(make_float2(f1.z, f1.w));
        uint4 u;
        u.x = *(unsigned*)&b01; u.y = *(unsigned*)&b23;
        u.z = *(unsigned*)&b45; u.w = *(unsigned*)&b67;
        *(uint4*)&As[r * 136 + kb * 8] = u;
    }

    const __hip_bfloat16* Ws[3] = { Wqt, Wkt, Wvt };

    #pragma unroll
    for (int w = 0; w < 3; ++w) {
        #pragma unroll
        for (int it = 0; it < 8; ++it) {
            int i = tid + it * 256;
            int r = i >> 4, kb = i & 15;
            *(uint4*)&Bs[r * 136 + kb * 8] =
                *(const uint4*)&Ws[w][(size_t)r * 128 + kb * 8];
        }
        __syncthreads();

        f32x4 acc[8];
        #pragma unroll
        for (int t = 0; t < 8; ++t) acc[t] = (f32x4)0.f;

        const unsigned short* ap = &As[(wave * 16 + l15) * 136 + quad * 8];
        const unsigned short* bp = &Bs[l15 * 136 + quad * 8];
        #pragma unroll
        for (int ks = 0; ks < 4; ++ks) {
            bf16x8 a = *(const bf16x8*)(ap + ks * 32);
            #pragma unroll
            for (int t = 0; t < 8; ++t) {
                bf16x8 b = *(const bf16x8*)(bp + t * 16 * 136 + ks * 32);
                acc[t] = __builtin_amdgcn_mfma_f32_16x16x32_bf16(a, b, acc[t], 0, 0, 0);
            }
        }
        __syncthreads();

        const int rbase = row0 + wave * 16 + quad * 4;
        #pragma unroll
        for (int i = 0; i < 4; ++i) {
            int row = rbase + i;
            if (row >= N) continue;
            #pragma unroll
            for (int t = 0; t < 8; ++t) {
                float v = acc[t][i];
                if (w == 0) {
                    ((_Float16*)Qh)[(size_t)row * 128 + t * 16 + l15] = (_Float16)v;
                } else if (w == 1) {
                    int pk = __builtin_amdgcn_cvt_pk_fp8_f32(v, 0.f, 0, false);
                    KV[(size_t)row * KVROW + t * 16 + l15] = (unsigned char)(pk & 0xff);
                } else {
                    *(__hip_bfloat16*)(KV + (size_t)row * KVROW + 128 +
                                       (t * 16 + l15) * 2) = __float2bfloat16(v);
                }
            }
        }
    }
}

// ---------------- MFMA GEMM (bf16 A) ----------------
// RB16: residual pointer is bf16 (Xh) instead of fp32.
template<int K, int YLOOP, bool RELU, bool LN, bool RESID, bool BIAS, bool RB16>
__global__ __launch_bounds__(256)
void gemm_mfma(const __hip_bfloat16* __restrict__ Ab, int lda,
               const __hip_bfloat16* __restrict__ Bt, int ldbt,
               const float* __restrict__ bias, const void* __restrict__ resid,
               const float* __restrict__ lng, const float* __restrict__ lnb,
               float* __restrict__ Cf, __hip_bfloat16* __restrict__ Cb, int ldc,
               int N)
{
    constexpr int CK = 128;
    static_assert(YLOOP == 1 || K == CK, "YLOOP>1 needs single K chunk");
    __shared__ unsigned short As[64 * 136];
    __shared__ unsigned short Bs[128 * 136];

    const int tid  = threadIdx.x;
    const int row0 = blockIdx.x * 64;
    const int wave = tid >> 6, lane = tid & 63;
    const int quad = lane >> 4, l15 = lane & 15;
    const int rbase = row0 + wave * 16 + quad * 4;

    for (int yy = 0; yy < YLOOP; ++yy) {
        const int col0 = yy * 128;

        f32x4 acc[8];
        #pragma unroll
        for (int t = 0; t < 8; ++t) acc[t] = (f32x4)0.f;

        for (int kc = 0; kc < K; kc += CK) {
            if (yy == 0) {
                #pragma unroll
                for (int it = 0; it < 4; ++it) {          // A: 64 x 128
                    int i = tid + it * 256;
                    int r = i >> 4, kb = i & 15;
                    int rg = row0 + r; if (rg > N - 1) rg = N - 1;
                    *(uint4*)&As[r * 136 + kb * 8] =
                        *(const uint4*)&Ab[(size_t)rg * lda + kc + kb * 8];
                }
            }
            #pragma unroll
            for (int it = 0; it < 8; ++it) {              // Bt: 128 x 128
                int i = tid + it * 256;
                int r = i >> 4, kb = i & 15;
                *(uint4*)&Bs[r * 136 + kb * 8] =
                    *(const uint4*)&Bt[(size_t)(col0 + r) * ldbt + kc + kb * 8];
            }
            __syncthreads();
            const unsigned short* ap = &As[(wave * 16 + l15) * 136 + quad * 8];
            const unsigned short* bp = &Bs[l15 * 136 + quad * 8];
            #pragma unroll
            for (int ks = 0; ks < 4; ++ks) {
                bf16x8 a = *(const bf16x8*)(ap + ks * 32);
                #pragma unroll
                for (int t = 0; t < 8; ++t) {
                    bf16x8 b = *(const bf16x8*)(bp + t * 16 * 136 + ks * 32);
                    acc[t] = __builtin_amdgcn_mfma_f32_16x16x32_bf16(a, b, acc[t], 0, 0, 0);
                }
            }
            __syncthreads();
        }

        float vals[8][4];
        #pragma unroll
        for (int t = 0; t < 8; ++t) {
            float bv = BIAS ? bias[col0 + t * 16 + l15] : 0.f;
            #pragma unroll
            for (int i = 0; i < 4; ++i) vals[t][i] = acc[t][i] + bv;
        }
        if (RESID) {
            #pragma unroll
            for (int i = 0; i < 4; ++i) {
                int row = rbase + i;
                if (row < N) {
                    if (RB16) {
                        const unsigned short* rb = (const unsigned short*)resid;
                        #pragma unroll
                        for (int t = 0; t < 8; ++t)
                            vals[t][i] += __uint_as_float(
                                (unsigned)rb[(size_t)row * 128 + t * 16 + l15] << 16);
                    } else {
                        const float* rf = (const float*)resid;
                        #pragma unroll
                        for (int t = 0; t < 8; ++t)
                            vals[t][i] += rf[(size_t)row * 128 + t * 16 + l15];
                    }
                }
            }
        }
        if (RELU) {
            #pragma unroll
            for (int t = 0; t < 8; ++t)
                #pragma unroll
                for (int i = 0; i < 4; ++i) vals[t][i] = fmaxf(vals[t][i], 0.f);
        }
        if (LN) {
            #pragma unroll
            for (int i = 0; i < 4; ++i) {
                float s = 0.f, sq = 0.f;
                #pragma unroll
                for (int t = 0; t < 8; ++t) { float v = vals[t][i]; s += v; sq += v * v; }
                s  += __shfl_xor(s, 1);  s  += __shfl_xor(s, 2);
                s  += __shfl_xor(s, 4);  s  += __shfl_xor(s, 8);
                sq += __shfl_xor(sq, 1); sq += __shfl_xor(sq, 2);
                sq += __shfl_xor(sq, 4); sq += __shfl_xor(sq, 8);
                float m  = s * (1.f / 128.f);
                float rs = rsqrtf(sq * (1.f / 128.f) - m * m + 1e-5f);
                #pragma unroll
                for (int t = 0; t < 8; ++t) {
                    float g = lng[t * 16 + l15], b = lnb[t * 16 + l15];
                    vals[t][i] = (vals[t][i] - m) * rs * g + b;
                }
            }
        }
        #pragma unroll
        for (int i = 0; i < 4; ++i) {
            int row = rbase + i;
            if (row >= N) continue;
            if (Cf) {
                #pragma unroll
                for (int t = 0; t < 8; ++t)
                    Cf[(size_t)row * ldc + col0 + t * 16 + l15] = vals[t][i];
            }
            if (Cb) {
                #pragma unroll
                for (int t = 0; t < 8; ++t)
                    Cb[(size_t)row * ldc + col0 + t * 16 + l15] =
                        __float2bfloat16(vals[t][i]);
            }
        }
    }
}

// ---------------- weight cast+transpose (+ bCnt zero) ----------------
struct WArgs {
    const float* src[6];
    __hip_bfloat16* dst[6];
    int R[6], C[6];
};
__global__ __launch_bounds__(256)
void cast_w(WArgs wa, int* __restrict__ bCnt)
{
    if (blockIdx.x == 0 && blockIdx.y == 0) bCnt[threadIdx.x] = 0;
    int w = blockIdx.y;
    int R = wa.R[w], C = wa.C[w];
    int i = blockIdx.x * 256 + threadIdx.x;
    if (i >= R * C) return;
    int sh = (C == 256) ? 8 : 7;
    int r = i >> sh, c = i & (C - 1);
    wa.dst[w][(size_t)c * R + r] = __float2bfloat16(wa.src[w][i]);
}

// ---------------- two-level bucketed sort of edges by dst ----------------
__global__ __launch_bounds__(256)
void bucket_hist(const int* __restrict__ dst, int* __restrict__ bCnt,
                 int E, int chunk, int NB)
{
    __shared__ int bh[256];
    const int t = threadIdx.x;
    bh[t] = 0;
    __syncthreads();
    const int s0 = blockIdx.x * chunk;
    const int s1 = min(E, s0 + chunk);
    for (int i = s0 + t; i < s1; i += 256)
        atomicAdd(&bh[dst[i] >> BSHIFT], 1);
    __syncthreads();
    if (t < NB && bh[t]) atomicAdd(&bCnt[t], bh[t]);
}

__global__ __launch_bounds__(256)
void bucket_scan(const int* __restrict__ bCnt, int* __restrict__ bBase,
                 int* __restrict__ gCur, int* __restrict__ rowStart,
                 int N, int E, int NB)
{
    __shared__ int wsum[4];
    const int t = threadIdx.x, lane = t & 63, wv = t >> 6;
    int v = (t < NB) ? bCnt[t] : 0;
    const int s = v;
    for (int off = 1; off < 64; off <<= 1) {
        int u = __shfl_up(v, off);
        if (lane >= off) v += u;
    }
    if (lane == 63) wsum[wv] = v;
    __syncthreads();
    int add = 0;
    for (int w = 0; w < wv; ++w) add += wsum[w];
    const int excl = v + add - s;
    if (t <= NB) bBase[t] = excl;
    if (t < NB)  gCur[t]  = excl;
    if (t == 0)  rowStart[N] = E;
}

__global__ __launch_bounds__(256)
void partition_kernel(const int* __restrict__ src, const int* __restrict__ dst,
                      int* __restrict__ gCur, uint2* __restrict__ P,
                      int E, int chunk, int NB)
{
    __shared__ int ch[256];
    __shared__ int cur[256];
    const int t = threadIdx.x;
    ch[t] = 0;
    __syncthreads();
    const int s0 = blockIdx.x * chunk;
    const int s1 = min(E, s0 + chunk);
    for (int i = s0 + t; i < s1; i += 256)
        atomicAdd(&ch[dst[i] >> BSHIFT], 1);
    __syncthreads();
    if (t < NB) {
        int c = ch[t];
        cur[t] = c ? atomicAdd(&gCur[t], c) : 0;
    }
    __syncthreads();
    for (int i = s0 + t; i < s1; i += 256) {
        int d = dst[i];
        int pos = atomicAdd(&cur[d >> BSHIFT], 1);
        P[pos] = make_uint2((unsigned)src[i], (unsigned)d);
    }
}

__global__ __launch_bounds__(256)
void bucket_scatter(const uint2* __restrict__ P, const int* __restrict__ bBase,
                    int* __restrict__ rowStart, int* __restrict__ esrc, int N)
{
    __shared__ int hist[BSIZE];
    __shared__ int cur[BSIZE];
    __shared__ int wsum[4];

    const int b  = blockIdx.x;
    const int t  = threadIdx.x;
    const int d0 = b << BSHIFT;
    const int bb  = bBase[b];
    const int cnt = bBase[b + 1] - bb;

    hist[t] = 0; hist[t + 256] = 0;
    __syncthreads();
    for (int i = t; i < cnt; i += 256)
        atomicAdd(&hist[(int)P[bb + i].y - d0], 1);
    __syncthreads();

    {
        const int a0 = hist[2 * t], a1 = hist[2 * t + 1];
        int v = a0 + a1;
        const int s = v;
        const int lane = t & 63, wv = t >> 6;
        for (int off = 1; off < 64; off <<= 1) {
            int u = __shfl_up(v, off);
            if (lane >= off) v += u;
        }
        if (lane == 63) wsum[wv] = v;
        __syncthreads();
        int add = 0;
        for (int w = 0; w < wv; ++w) add += wsum[w];
        const int exclT = v + add - s;
        cur[2 * t]     = exclT;
        cur[2 * t + 1] = exclT + a0;
    }
    __syncthreads();
    for (int i = t; i < BSIZE; i += 256) {
        int d = d0 + i;
        if (d < N) rowStart[d] = bb + cur[i];
    }
    __syncthreads();
    for (int i = t; i < cnt; i += 256) {
        uint2 p = P[bb + i];
        int pos = atomicAdd(&cur[(int)p.y - d0], 1);
        esrc[bb + pos] = (int)p.x;
    }
}

// ---------------- aggregation ----------------
// wave = 4 dst-groups of 16 lanes; 8 edges per iteration (2 per group).
// KV row: 128 B fp8 K + 256 B bf16 V. K decoded via v_cvt_pk_f32_fp8.
__global__ __launch_bounds__(256)
void aggregate_kernel(unsigned short* __restrict__ Qp,
                      const unsigned char* __restrict__ KV,
                      const int* __restrict__ esrc,
                      const int* __restrict__ rowStart, int N)
{
    const int lane = threadIdx.x & 63;
    const int wid  = threadIdx.x >> 6;
    const int d    = blockIdx.x * 4 + wid;
    if (d >= N) return;

    const int c = lane & 15;      // chunk: elems [c*8, c*8+8), head = c>>1
    const int g = lane >> 4;      // edge slot 0..3

    const uint4 qraw = *(const uint4*)(Qp + (size_t)d * 128u + c * 8);
    const half2_t q0 = h2(qraw.x), q1 = h2(qraw.y),
                  q2 = h2(qraw.z), q3 = h2(qraw.w);
    const float qf0 = (float)q0.x, qf1 = (float)q0.y;
    const float qf2 = (float)q1.x, qf3 = (float)q1.y;
    const float qf4 = (float)q2.x, qf5 = (float)q2.y;
    const float qf6 = (float)q3.x, qf7 = (float)q3.y;

    const int beg = rowStart[d];
    const int end = rowStart[d + 1];
    const int endm1 = end - 1;

    float a0 = 0.f, a1 = 0.f, a2 = 0.f, a3 = 0.f;
    float a4 = 0.f, a5 = 0.f, a6 = 0.f, a7 = 0.f, z = 0.f;
    const float S = 0.36067376022224085f;  // 0.25 * log2(e)
    const float C = 7.2134752044448170f;   // 5 * log2(e)

    const int nIt = (end - beg + 7) >> 3;
    #pragma unroll 2
    for (int it = 0; it < nIt; ++it) {
        const int ea = beg + it * 8 + g;
        const int eb = ea + 4;
        const bool va = ea < end;
        const bool vb = eb < end;
        const int sa = esrc[va ? ea : endm1];
        const int sb = esrc[vb ? eb : endm1];
        const unsigned char* pa = KV + (size_t)(unsigned)sa * (size_t)KVROW;
        const unsigned char* pb = KV + (size_t)(unsigned)sb * (size_t)KVROW;
        const uint2 ka = *(const uint2*)(pa + c * 8);          // K fp8 x8
        const uint4 vra = *(const uint4*)(pa + 128 + c * 16);  // V bf16 x8
        const uint2 kb = *(const uint2*)(pb + c * 8);
        const uint4 vrb = *(const uint4*)(pb + 128 + c * 16);

        auto ka01 = __builtin_amdgcn_cvt_pk_f32_fp8(ka.x, false);
        auto ka23 = __builtin_amdgcn_cvt_pk_f32_fp8(ka.x, true);
        auto ka45 = __builtin_amdgcn_cvt_pk_f32_fp8(ka.y, false);
        auto ka67 = __builtin_amdgcn_cvt_pk_f32_fp8(ka.y, true);
        float p = ka01[0] * qf0 + ka01[1] * qf1 + ka23[0] * qf2 + ka23[1] * qf3
                + ka45[0] * qf4 + ka45[1] * qf5 + ka67[0] * qf6 + ka67[1] * qf7;
        p += __shfl_xor(p, 1);                       // head = 2 lanes
        float se = exp2f(fminf(C, fmaxf(-C, p * S)));
        se = va ? se : 0.f;

        auto kb01 = __builtin_amdgcn_cvt_pk_f32_fp8(kb.x, false);
        auto kb23 = __builtin_amdgcn_cvt_pk_f32_fp8(kb.x, true);
        auto kb45 = __builtin_amdgcn_cvt_pk_f32_fp8(kb.y, false);
        auto kb67 = __builtin_amdgcn_cvt_pk_f32_fp8(kb.y, true);
        float p2 = kb01[0] * qf0 + kb01[1] * qf1 + kb23[0] * qf2 + kb23[1] * qf3
                 + kb45[0] * qf4 + kb45[1] * qf5 + kb67[0] * qf6 + kb67[1] * qf7;
        p2 += __shfl_xor(p2, 1);
        float se2 = exp2f(fminf(C, fmaxf(-C, p2 * S)));
        se2 = vb ? se2 : 0.f;

        a0 += bl(vra.x) * se; a1 += bh(vra.x) * se;
        a2 += bl(vra.y) * se; a3 += bh(vra.y) * se;
        a4 += bl(vra.z) * se; a5 += bh(vra.z) * se;
        a6 += bl(vra.w) * se; a7 += bh(vra.w) * se;
        z  += se;

        a0 += bl(vrb.x) * se2; a1 += bh(vrb.x) * se2;
        a2 += bl(vrb.y) * se2; a3 += bh(vrb.y) * se2;
        a4 += bl(vrb.z) * se2; a5 += bh(vrb.z) * se2;
        a6 += bl(vrb.w) * se2; a7 += bh(vrb.w) * se2;
        z  += se2;
    }

    a0 += __shfl_xor(a0, 16); a1 += __shfl_xor(a1, 16);
    a2 += __shfl_xor(a2, 16); a3 += __shfl_xor(a3, 16);
    a4 += __shfl_xor(a4, 16); a5 += __shfl_xor(a5, 16);
    a6 += __shfl_xor(a6, 16); a7 += __shfl_xor(a7, 16);
    z  += __shfl_xor(z, 16);
    a0 += __shfl_xor(a0, 32); a1 += __shfl_xor(a1, 32);
    a2 += __shfl_xor(a2, 32); a3 += __shfl_xor(a3, 32);
    a4 += __shfl_xor(a4, 32); a5 += __shfl_xor(a5, 32);
    a6 += __shfl_xor(a6, 32); a7 += __shfl_xor(a7, 32);
    z  += __shfl_xor(z, 32);

    if (g == 0) {
        const float inv = 1.0f / (z + 1e-6f);
        __hip_bfloat162 p0 = __float22bfloat162_rn(make_float2(a0 * inv, a1 * inv));
        __hip_bfloat162 p1 = __float22bfloat162_rn(make_float2(a2 * inv, a3 * inv));
        __hip_bfloat162 p2 = __float22bfloat162_rn(make_float2(a4 * inv, a5 * inv));
        __hip_bfloat162 p3 = __float22bfloat162_rn(make_float2(a6 * inv, a7 * inv));
        uint4 o;
        o.x = *(unsigned*)&p0; o.y = *(unsigned*)&p1;
        o.z = *(unsigned*)&p2; o.w = *(unsigned*)&p3;
        *(uint4*)(Qp + (size_t)d * 128u + c * 8) = o;
    }
}

// =====================================================================
extern "C" void kernel_launch(void* const* d_in, const int* in_sizes, int n_in,
                              void* d_out, int out_size, void* d_ws, size_t ws_size,
                              hipStream_t stream)
{
    const float* h    = (const float*)d_in[0];
    const int*   src  = (const int*)  d_in[1];
    const int*   dst  = (const int*)  d_in[2];
    const float* Wq   = (const float*)d_in[3];
    const float* Wk   = (const float*)d_in[4];
    const float* Wv   = (const float*)d_in[5];
    const float* Wo   = (const float*)d_in[6];
    const float* bo   = (const float*)d_in[7];
    const float* ln1g = (const float*)d_in[8];
    const float* ln1b = (const float*)d_in[9];
    const float* W1   = (const float*)d_in[10];
    const float* b1   = (const float*)d_in[11];
    const float* W2   = (const float*)d_in[12];
    const float* b2   = (const float*)d_in[13];
    const float* ln2g = (const float*)d_in[14];
    const float* ln2b = (const float*)d_in[15];

    const int N = in_sizes[0] / 128;
    const int E = in_sizes[1];
    const int NB = (N + BSIZE - 1) >> BSHIFT;

    // ---- workspace layout ----
    unsigned short* Qh = (unsigned short*)d_ws;          // N*128 f16 (Q), bf16 h_attn after agg
    unsigned char*  KVc = (unsigned char*)(Qh + (size_t)N * 128);  // N*384 B: K fp8 | V bf16
    __hip_bfloat16* Xh = (__hip_bfloat16*)(KVc + (size_t)N * KVROW);  // N*128 bf16 (LN1 out)
    __hip_bfloat16* Wt = (__hip_bfloat16*)(Xh + (size_t)N * 128);
    __hip_bfloat16* Wqt = Wt;
    __hip_bfloat16* Wkt = Wqt + 16384;
    __hip_bfloat16* Wvt = Wkt + 16384;
    __hip_bfloat16* Wot = Wvt + 16384;
    __hip_bfloat16* W1t = Wot + 16384;        // [256][128]
    __hip_bfloat16* W2t = W1t + 32768;        // [128][256]
    int* ib       = (int*)(W2t + 32768);
    int* bCnt     = ib;                       // 256
    int* bBase    = ib + 256;                 // 257
    int* gCur     = ib + 514;                 // 256
    int* rowStart = ib + 770;                 // N+1
    int* esrc     = ib + 770 + N + 2;         // E
    uint2* P      = (uint2*)Xh;               // E pairs overlay Xh (dead during sort;
                                              //   Xh written only by LN1, after sort+agg)
    __hip_bfloat16* Th = (__hip_bfloat16*)Qh; // N*256 bf16 overlay on Qh+KVc (N*640 B
                                              //   region; both dead after LN1 consumes Qh)

    const dim3 blk(256);
    const int  nb    = (N + 63) / 64;
    const int  chunk = (E + 255) / 256;

    // ---- weight cast+transpose (+ bCnt zero) ----
    WArgs wa;
    wa.src[0] = Wq; wa.src[1] = Wk; wa.src[2] = Wv; wa.src[3] = Wo; wa.src[4] = W1; wa.src[5] = W2;
    wa.dst[0] = Wqt; wa.dst[1] = Wkt; wa.dst[2] = Wvt; wa.dst[3] = Wot; wa.dst[4] = W1t; wa.dst[5] = W2t;
    wa.R[0] = wa.R[1] = wa.R[2] = wa.R[3] = 128; wa.R[4] = 128; wa.R[5] = 256;
    wa.C[0] = wa.C[1] = wa.C[2] = wa.C[3] = 128; wa.C[4] = 256; wa.C[5] = 128;
    cast_w<<<dim3(128, 6), blk, 0, stream>>>(wa, bCnt);

    // ---- fused QKV (h read once) ----
    qkv_fused<<<dim3(nb), blk, 0, stream>>>(h, Wqt, Wkt, Wvt, Qh, KVc, N);

    // ---- bucketed sort of edges by dst ----
    bucket_hist<<<dim3(256), blk, 0, stream>>>(dst, bCnt, E, chunk, NB);
    bucket_scan<<<dim3(1), blk, 0, stream>>>(bCnt, bBase, gCur, rowStart, N, E, NB);
    partition_kernel<<<dim3(256), blk, 0, stream>>>(src, dst, gCur, P, E, chunk, NB);
    bucket_scatter<<<dim3(NB), blk, 0, stream>>>(P, bBase, rowStart, esrc, N);

    // ---- aggregate (reads f16 Q + fp8 K + bf16 V, writes bf16 h_attn into Qh) ----
    aggregate_kernel<<<dim3((N + 3) / 4), blk, 0, stream>>>(Qh, KVc, esrc, rowStart, N);

    // ---- X = LN1(h + h_attn@Wo + bo) -> bf16 Xh only ----
    gemm_mfma<128,1,false,true,true,true,false><<<dim3(nb), blk, 0, stream>>>(
        (const __hip_bfloat16*)Qh, 128, Wot, 128, bo, h, ln1g, ln1b,
        nullptr, Xh, 128, N);

    // ---- T = relu(X@W1 + b1) -> bf16 (both column halves in one block) ----
    gemm_mfma<128,2,true,false,false,true,false><<<dim3(nb), blk, 0, stream>>>(
        Xh, 128, W1t, 128, b1, nullptr, nullptr, nullptr,
        nullptr, Th, 256, N);

    // ---- out = LN2(X(bf16) + T@W2 + b2) -> fp32 ----
    gemm_mfma<256,1,false,true,true,true,true><<<dim3(nb), blk, 0, stream>>>(
        Th, 256, W2t, 256, b2, Xh, ln2g, ln2b,
        (float*)d_out, nullptr, 128, N);
}

// Round 9
// 359.785 us; speedup vs baseline: 1.2889x; 1.0628x over previous
//
#include <hip/hip_runtime.h>
#include <hip/hip_bf16.h>
#include <math.h>

// =====================================================================
// GraphTransformerLayer, round 12
//   - V stored as fp8 e4m3 too: KV row 256 B = [128 B K fp8 | 128 B V
//     fp8]. Edge gather 384 -> 256 B. Wall model (time = FETCH/3.7T,
//     verified r9/r11) predicts aggregate 87 -> ~63 us; VALU floor ~56
//     us is the new corner (cvt_pk_f32_fp8 decode replaces bf16 unpack,
//     VALU-neutral).
//   - Th overlay = Qh+KVc exactly (N*512 B, both dead after LN1).
//   - everything else unchanged from r11 (382.4 us, absmax 0.0859).
// =====================================================================

typedef __attribute__((ext_vector_type(8))) short bf16x8;
typedef __attribute__((ext_vector_type(4))) float f32x4;
typedef __attribute__((ext_vector_type(2))) _Float16 half2_t;

#define BSHIFT 9
#define BSIZE  512
#define KVROW  256

static __device__ __forceinline__ half2_t h2(unsigned u) {
    return __builtin_bit_cast(half2_t, u);
}

// ---------------- fused QKV GEMM ----------------
// Q -> f16 [N][128]; K -> fp8 e4m3 at KV+row*256; V -> fp8 at +128.
__global__ __launch_bounds__(256)
void qkv_fused(const float* __restrict__ h,
               const __hip_bfloat16* __restrict__ Wqt,
               const __hip_bfloat16* __restrict__ Wkt,
               const __hip_bfloat16* __restrict__ Wvt,
               unsigned short* __restrict__ Qh,
               unsigned char* __restrict__ KV,
               int N)
{
    __shared__ unsigned short As[64 * 136];
    __shared__ unsigned short Bs[128 * 136];

    const int tid  = threadIdx.x;
    const int row0 = blockIdx.x * 64;
    const int wave = tid >> 6, lane = tid & 63;
    const int quad = lane >> 4, l15 = lane & 15;

    #pragma unroll
    for (int it = 0; it < 4; ++it) {
        int i = tid + it * 256;
        int r = i >> 4, kb = i & 15;
        int rg = row0 + r; if (rg > N - 1) rg = N - 1;
        const float4 f0 = *(const float4*)&h[(size_t)rg * 128 + kb * 8];
        const float4 f1 = *(const float4*)&h[(size_t)rg * 128 + kb * 8 + 4];
        __hip_bfloat162 b01 = __float22bfloat162_rn(make_float2(f0.x, f0.y));
        __hip_bfloat162 b23 = __float22bfloat162_rn(make_float2(f0.z, f0.w));
        __hip_bfloat162 b45 = __float22bfloat162_rn(make_float2(f1.x, f1.y));
        __hip_bfloat162 b67 = __float22bfloat162_rn(make_float2(f1.z, f1.w));
        uint4 u;
        u.x = *(unsigned*)&b01; u.y = *(unsigned*)&b23;
        u.z = *(unsigned*)&b45; u.w = *(unsigned*)&b67;
        *(uint4*)&As[r * 136 + kb * 8] = u;
    }

    const __hip_bfloat16* Ws[3] = { Wqt, Wkt, Wvt };

    #pragma unroll
    for (int w = 0; w < 3; ++w) {
        #pragma unroll
        for (int it = 0; it < 8; ++it) {
            int i = tid + it * 256;
            int r = i >> 4, kb = i & 15;
            *(uint4*)&Bs[r * 136 + kb * 8] =
                *(const uint4*)&Ws[w][(size_t)r * 128 + kb * 8];
        }
        __syncthreads();

        f32x4 acc[8];
        #pragma unroll
        for (int t = 0; t < 8; ++t) acc[t] = (f32x4)0.f;

        const unsigned short* ap = &As[(wave * 16 + l15) * 136 + quad * 8];
        const unsigned short* bp = &Bs[l15 * 136 + quad * 8];
        #pragma unroll
        for (int ks = 0; ks < 4; ++ks) {
            bf16x8 a = *(const bf16x8*)(ap + ks * 32);
            #pragma unroll
            for (int t = 0; t < 8; ++t) {
                bf16x8 b = *(const bf16x8*)(bp + t * 16 * 136 + ks * 32);
                acc[t] = __builtin_amdgcn_mfma_f32_16x16x32_bf16(a, b, acc[t], 0, 0, 0);
            }
        }
        __syncthreads();

        const int rbase = row0 + wave * 16 + quad * 4;
        #pragma unroll
        for (int i = 0; i < 4; ++i) {
            int row = rbase + i;
            if (row >= N) continue;
            #pragma unroll
            for (int t = 0; t < 8; ++t) {
                float v = acc[t][i];
                if (w == 0) {
                    ((_Float16*)Qh)[(size_t)row * 128 + t * 16 + l15] = (_Float16)v;
                } else {
                    int pk = __builtin_amdgcn_cvt_pk_fp8_f32(v, 0.f, 0, false);
                    KV[(size_t)row * KVROW + (w == 1 ? 0 : 128) + t * 16 + l15] =
                        (unsigned char)(pk & 0xff);
                }
            }
        }
    }
}

// ---------------- MFMA GEMM (bf16 A) ----------------
// RB16: residual pointer is bf16 (Xh) instead of fp32.
template<int K, int YLOOP, bool RELU, bool LN, bool RESID, bool BIAS, bool RB16>
__global__ __launch_bounds__(256)
void gemm_mfma(const __hip_bfloat16* __restrict__ Ab, int lda,
               const __hip_bfloat16* __restrict__ Bt, int ldbt,
               const float* __restrict__ bias, const void* __restrict__ resid,
               const float* __restrict__ lng, const float* __restrict__ lnb,
               float* __restrict__ Cf, __hip_bfloat16* __restrict__ Cb, int ldc,
               int N)
{
    constexpr int CK = 128;
    static_assert(YLOOP == 1 || K == CK, "YLOOP>1 needs single K chunk");
    __shared__ unsigned short As[64 * 136];
    __shared__ unsigned short Bs[128 * 136];

    const int tid  = threadIdx.x;
    const int row0 = blockIdx.x * 64;
    const int wave = tid >> 6, lane = tid & 63;
    const int quad = lane >> 4, l15 = lane & 15;
    const int rbase = row0 + wave * 16 + quad * 4;

    for (int yy = 0; yy < YLOOP; ++yy) {
        const int col0 = yy * 128;

        f32x4 acc[8];
        #pragma unroll
        for (int t = 0; t < 8; ++t) acc[t] = (f32x4)0.f;

        for (int kc = 0; kc < K; kc += CK) {
            if (yy == 0) {
                #pragma unroll
                for (int it = 0; it < 4; ++it) {          // A: 64 x 128
                    int i = tid + it * 256;
                    int r = i >> 4, kb = i & 15;
                    int rg = row0 + r; if (rg > N - 1) rg = N - 1;
                    *(uint4*)&As[r * 136 + kb * 8] =
                        *(const uint4*)&Ab[(size_t)rg * lda + kc + kb * 8];
                }
            }
            #pragma unroll
            for (int it = 0; it < 8; ++it) {              // Bt: 128 x 128
                int i = tid + it * 256;
                int r = i >> 4, kb = i & 15;
                *(uint4*)&Bs[r * 136 + kb * 8] =
                    *(const uint4*)&Bt[(size_t)(col0 + r) * ldbt + kc + kb * 8];
            }
            __syncthreads();
            const unsigned short* ap = &As[(wave * 16 + l15) * 136 + quad * 8];
            const unsigned short* bp = &Bs[l15 * 136 + quad * 8];
            #pragma unroll
            for (int ks = 0; ks < 4; ++ks) {
                bf16x8 a = *(const bf16x8*)(ap + ks * 32);
                #pragma unroll
                for (int t = 0; t < 8; ++t) {
                    bf16x8 b = *(const bf16x8*)(bp + t * 16 * 136 + ks * 32);
                    acc[t] = __builtin_amdgcn_mfma_f32_16x16x32_bf16(a, b, acc[t], 0, 0, 0);
                }
            }
            __syncthreads();
        }

        float vals[8][4];
        #pragma unroll
        for (int t = 0; t < 8; ++t) {
            float bv = BIAS ? bias[col0 + t * 16 + l15] : 0.f;
            #pragma unroll
            for (int i = 0; i < 4; ++i) vals[t][i] = acc[t][i] + bv;
        }
        if (RESID) {
            #pragma unroll
            for (int i = 0; i < 4; ++i) {
                int row = rbase + i;
                if (row < N) {
                    if (RB16) {
                        const unsigned short* rb = (const unsigned short*)resid;
                        #pragma unroll
                        for (int t = 0; t < 8; ++t)
                            vals[t][i] += __uint_as_float(
                                (unsigned)rb[(size_t)row * 128 + t * 16 + l15] << 16);
                    } else {
                        const float* rf = (const float*)resid;
                        #pragma unroll
                        for (int t = 0; t < 8; ++t)
                            vals[t][i] += rf[(size_t)row * 128 + t * 16 + l15];
                    }
                }
            }
        }
        if (RELU) {
            #pragma unroll
            for (int t = 0; t < 8; ++t)
                #pragma unroll
                for (int i = 0; i < 4; ++i) vals[t][i] = fmaxf(vals[t][i], 0.f);
        }
        if (LN) {
            #pragma unroll
            for (int i = 0; i < 4; ++i) {
                float s = 0.f, sq = 0.f;
                #pragma unroll
                for (int t = 0; t < 8; ++t) { float v = vals[t][i]; s += v; sq += v * v; }
                s  += __shfl_xor(s, 1);  s  += __shfl_xor(s, 2);
                s  += __shfl_xor(s, 4);  s  += __shfl_xor(s, 8);
                sq += __shfl_xor(sq, 1); sq += __shfl_xor(sq, 2);
                sq += __shfl_xor(sq, 4); sq += __shfl_xor(sq, 8);
                float m  = s * (1.f / 128.f);
                float rs = rsqrtf(sq * (1.f / 128.f) - m * m + 1e-5f);
                #pragma unroll
                for (int t = 0; t < 8; ++t) {
                    float g = lng[t * 16 + l15], b = lnb[t * 16 + l15];
                    vals[t][i] = (vals[t][i] - m) * rs * g + b;
                }
            }
        }
        #pragma unroll
        for (int i = 0; i < 4; ++i) {
            int row = rbase + i;
            if (row >= N) continue;
            if (Cf) {
                #pragma unroll
                for (int t = 0; t < 8; ++t)
                    Cf[(size_t)row * ldc + col0 + t * 16 + l15] = vals[t][i];
            }
            if (Cb) {
                #pragma unroll
                for (int t = 0; t < 8; ++t)
                    Cb[(size_t)row * ldc + col0 + t * 16 + l15] =
                        __float2bfloat16(vals[t][i]);
            }
        }
    }
}

// ---------------- weight cast+transpose (+ bCnt zero) ----------------
struct WArgs {
    const float* src[6];
    __hip_bfloat16* dst[6];
    int R[6], C[6];
};
__global__ __launch_bounds__(256)
void cast_w(WArgs wa, int* __restrict__ bCnt)
{
    if (blockIdx.x == 0 && blockIdx.y == 0) bCnt[threadIdx.x] = 0;
    int w = blockIdx.y;
    int R = wa.R[w], C = wa.C[w];
    int i = blockIdx.x * 256 + threadIdx.x;
    if (i >= R * C) return;
    int sh = (C == 256) ? 8 : 7;
    int r = i >> sh, c = i & (C - 1);
    wa.dst[w][(size_t)c * R + r] = __float2bfloat16(wa.src[w][i]);
}

// ---------------- two-level bucketed sort of edges by dst ----------------
__global__ __launch_bounds__(256)
void bucket_hist(const int* __restrict__ dst, int* __restrict__ bCnt,
                 int E, int chunk, int NB)
{
    __shared__ int bh[256];
    const int t = threadIdx.x;
    bh[t] = 0;
    __syncthreads();
    const int s0 = blockIdx.x * chunk;
    const int s1 = min(E, s0 + chunk);
    for (int i = s0 + t; i < s1; i += 256)
        atomicAdd(&bh[dst[i] >> BSHIFT], 1);
    __syncthreads();
    if (t < NB && bh[t]) atomicAdd(&bCnt[t], bh[t]);
}

__global__ __launch_bounds__(256)
void bucket_scan(const int* __restrict__ bCnt, int* __restrict__ bBase,
                 int* __restrict__ gCur, int* __restrict__ rowStart,
                 int N, int E, int NB)
{
    __shared__ int wsum[4];
    const int t = threadIdx.x, lane = t & 63, wv = t >> 6;
    int v = (t < NB) ? bCnt[t] : 0;
    const int s = v;
    for (int off = 1; off < 64; off <<= 1) {
        int u = __shfl_up(v, off);
        if (lane >= off) v += u;
    }
    if (lane == 63) wsum[wv] = v;
    __syncthreads();
    int add = 0;
    for (int w = 0; w < wv; ++w) add += wsum[w];
    const int excl = v + add - s;
    if (t <= NB) bBase[t] = excl;
    if (t < NB)  gCur[t]  = excl;
    if (t == 0)  rowStart[N] = E;
}

__global__ __launch_bounds__(256)
void partition_kernel(const int* __restrict__ src, const int* __restrict__ dst,
                      int* __restrict__ gCur, uint2* __restrict__ P,
                      int E, int chunk, int NB)
{
    __shared__ int ch[256];
    __shared__ int cur[256];
    const int t = threadIdx.x;
    ch[t] = 0;
    __syncthreads();
    const int s0 = blockIdx.x * chunk;
    const int s1 = min(E, s0 + chunk);
    for (int i = s0 + t; i < s1; i += 256)
        atomicAdd(&ch[dst[i] >> BSHIFT], 1);
    __syncthreads();
    if (t < NB) {
        int c = ch[t];
        cur[t] = c ? atomicAdd(&gCur[t], c) : 0;
    }
    __syncthreads();
    for (int i = s0 + t; i < s1; i += 256) {
        int d = dst[i];
        int pos = atomicAdd(&cur[d >> BSHIFT], 1);
        P[pos] = make_uint2((unsigned)src[i], (unsigned)d);
    }
}

__global__ __launch_bounds__(256)
void bucket_scatter(const uint2* __restrict__ P, const int* __restrict__ bBase,
                    int* __restrict__ rowStart, int* __restrict__ esrc, int N)
{
    __shared__ int hist[BSIZE];
    __shared__ int cur[BSIZE];
    __shared__ int wsum[4];

    const int b  = blockIdx.x;
    const int t  = threadIdx.x;
    const int d0 = b << BSHIFT;
    const int bb  = bBase[b];
    const int cnt = bBase[b + 1] - bb;

    hist[t] = 0; hist[t + 256] = 0;
    __syncthreads();
    for (int i = t; i < cnt; i += 256)
        atomicAdd(&hist[(int)P[bb + i].y - d0], 1);
    __syncthreads();

    {
        const int a0 = hist[2 * t], a1 = hist[2 * t + 1];
        int v = a0 + a1;
        const int s = v;
        const int lane = t & 63, wv = t >> 6;
        for (int off = 1; off < 64; off <<= 1) {
            int u = __shfl_up(v, off);
            if (lane >= off) v += u;
        }
        if (lane == 63) wsum[wv] = v;
        __syncthreads();
        int add = 0;
        for (int w = 0; w < wv; ++w) add += wsum[w];
        const int exclT = v + add - s;
        cur[2 * t]     = exclT;
        cur[2 * t + 1] = exclT + a0;
    }
    __syncthreads();
    for (int i = t; i < BSIZE; i += 256) {
        int d = d0 + i;
        if (d < N) rowStart[d] = bb + cur[i];
    }
    __syncthreads();
    for (int i = t; i < cnt; i += 256) {
        uint2 p = P[bb + i];
        int pos = atomicAdd(&cur[(int)p.y - d0], 1);
        esrc[bb + pos] = (int)p.x;
    }
}

// ---------------- aggregation ----------------
// wave = 4 dst-groups of 16 lanes; 8 edges per iteration (2 per group).
// KV row: 128 B fp8 K + 128 B fp8 V. Both decoded via v_cvt_pk_f32_fp8.
__global__ __launch_bounds__(256)
void aggregate_kernel(unsigned short* __restrict__ Qp,
                      const unsigned char* __restrict__ KV,
                      const int* __restrict__ esrc,
                      const int* __restrict__ rowStart, int N)
{
    const int lane = threadIdx.x & 63;
    const int wid  = threadIdx.x >> 6;
    const int d    = blockIdx.x * 4 + wid;
    if (d >= N) return;

    const int c = lane & 15;      // chunk: elems [c*8, c*8+8), head = c>>1
    const int g = lane >> 4;      // edge slot 0..3

    const uint4 qraw = *(const uint4*)(Qp + (size_t)d * 128u + c * 8);
    const half2_t q0 = h2(qraw.x), q1 = h2(qraw.y),
                  q2 = h2(qraw.z), q3 = h2(qraw.w);
    const float qf0 = (float)q0.x, qf1 = (float)q0.y;
    const float qf2 = (float)q1.x, qf3 = (float)q1.y;
    const float qf4 = (float)q2.x, qf5 = (float)q2.y;
    const float qf6 = (float)q3.x, qf7 = (float)q3.y;

    const int beg = rowStart[d];
    const int end = rowStart[d + 1];
    const int endm1 = end - 1;

    float a0 = 0.f, a1 = 0.f, a2 = 0.f, a3 = 0.f;
    float a4 = 0.f, a5 = 0.f, a6 = 0.f, a7 = 0.f, z = 0.f;
    const float S = 0.36067376022224085f;  // 0.25 * log2(e)
    const float C = 7.2134752044448170f;   // 5 * log2(e)

    const int nIt = (end - beg + 7) >> 3;
    #pragma unroll 2
    for (int it = 0; it < nIt; ++it) {
        const int ea = beg + it * 8 + g;
        const int eb = ea + 4;
        const bool va = ea < end;
        const bool vb = eb < end;
        const int sa = esrc[va ? ea : endm1];
        const int sb = esrc[vb ? eb : endm1];
        const unsigned char* pa = KV + (size_t)(unsigned)sa * (size_t)KVROW;
        const unsigned char* pb = KV + (size_t)(unsigned)sb * (size_t)KVROW;
        const uint2 ka = *(const uint2*)(pa + c * 8);         // K fp8 x8
        const uint2 vA = *(const uint2*)(pa + 128 + c * 8);   // V fp8 x8
        const uint2 kb = *(const uint2*)(pb + c * 8);
        const uint2 vB = *(const uint2*)(pb + 128 + c * 8);

        auto ka01 = __builtin_amdgcn_cvt_pk_f32_fp8(ka.x, false);
        auto ka23 = __builtin_amdgcn_cvt_pk_f32_fp8(ka.x, true);
        auto ka45 = __builtin_amdgcn_cvt_pk_f32_fp8(ka.y, false);
        auto ka67 = __builtin_amdgcn_cvt_pk_f32_fp8(ka.y, true);
        float p = ka01[0] * qf0 + ka01[1] * qf1 + ka23[0] * qf2 + ka23[1] * qf3
                + ka45[0] * qf4 + ka45[1] * qf5 + ka67[0] * qf6 + ka67[1] * qf7;
        p += __shfl_xor(p, 1);                       // head = 2 lanes
        float se = exp2f(fminf(C, fmaxf(-C, p * S)));
        se = va ? se : 0.f;

        auto kb01 = __builtin_amdgcn_cvt_pk_f32_fp8(kb.x, false);
        auto kb23 = __builtin_amdgcn_cvt_pk_f32_fp8(kb.x, true);
        auto kb45 = __builtin_amdgcn_cvt_pk_f32_fp8(kb.y, false);
        auto kb67 = __builtin_amdgcn_cvt_pk_f32_fp8(kb.y, true);
        float p2 = kb01[0] * qf0 + kb01[1] * qf1 + kb23[0] * qf2 + kb23[1] * qf3
                 + kb45[0] * qf4 + kb45[1] * qf5 + kb67[0] * qf6 + kb67[1] * qf7;
        p2 += __shfl_xor(p2, 1);
        float se2 = exp2f(fminf(C, fmaxf(-C, p2 * S)));
        se2 = vb ? se2 : 0.f;

        auto va01 = __builtin_amdgcn_cvt_pk_f32_fp8(vA.x, false);
        auto va23 = __builtin_amdgcn_cvt_pk_f32_fp8(vA.x, true);
        auto va45 = __builtin_amdgcn_cvt_pk_f32_fp8(vA.y, false);
        auto va67 = __builtin_amdgcn_cvt_pk_f32_fp8(vA.y, true);
        a0 += va01[0] * se; a1 += va01[1] * se;
        a2 += va23[0] * se; a3 += va23[1] * se;
        a4 += va45[0] * se; a5 += va45[1] * se;
        a6 += va67[0] * se; a7 += va67[1] * se;
        z  += se;

        auto vb01 = __builtin_amdgcn_cvt_pk_f32_fp8(vB.x, false);
        auto vb23 = __builtin_amdgcn_cvt_pk_f32_fp8(vB.x, true);
        auto vb45 = __builtin_amdgcn_cvt_pk_f32_fp8(vB.y, false);
        auto vb67 = __builtin_amdgcn_cvt_pk_f32_fp8(vB.y, true);
        a0 += vb01[0] * se2; a1 += vb01[1] * se2;
        a2 += vb23[0] * se2; a3 += vb23[1] * se2;
        a4 += vb45[0] * se2; a5 += vb45[1] * se2;
        a6 += vb67[0] * se2; a7 += vb67[1] * se2;
        z  += se2;
    }

    a0 += __shfl_xor(a0, 16); a1 += __shfl_xor(a1, 16);
    a2 += __shfl_xor(a2, 16); a3 += __shfl_xor(a3, 16);
    a4 += __shfl_xor(a4, 16); a5 += __shfl_xor(a5, 16);
    a6 += __shfl_xor(a6, 16); a7 += __shfl_xor(a7, 16);
    z  += __shfl_xor(z, 16);
    a0 += __shfl_xor(a0, 32); a1 += __shfl_xor(a1, 32);
    a2 += __shfl_xor(a2, 32); a3 += __shfl_xor(a3, 32);
    a4 += __shfl_xor(a4, 32); a5 += __shfl_xor(a5, 32);
    a6 += __shfl_xor(a6, 32); a7 += __shfl_xor(a7, 32);
    z  += __shfl_xor(z, 32);

    if (g == 0) {
        const float inv = 1.0f / (z + 1e-6f);
        __hip_bfloat162 p0 = __float22bfloat162_rn(make_float2(a0 * inv, a1 * inv));
        __hip_bfloat162 p1 = __float22bfloat162_rn(make_float2(a2 * inv, a3 * inv));
        __hip_bfloat162 p2 = __float22bfloat162_rn(make_float2(a4 * inv, a5 * inv));
        __hip_bfloat162 p3 = __float22bfloat162_rn(make_float2(a6 * inv, a7 * inv));
        uint4 o;
        o.x = *(unsigned*)&p0; o.y = *(unsigned*)&p1;
        o.z = *(unsigned*)&p2; o.w = *(unsigned*)&p3;
        *(uint4*)(Qp + (size_t)d * 128u + c * 8) = o;
    }
}

// =====================================================================
extern "C" void kernel_launch(void* const* d_in, const int* in_sizes, int n_in,
                              void* d_out, int out_size, void* d_ws, size_t ws_size,
                              hipStream_t stream)
{
    const float* h    = (const float*)d_in[0];
    const int*   src  = (const int*)  d_in[1];
    const int*   dst  = (const int*)  d_in[2];
    const float* Wq   = (const float*)d_in[3];
    const float* Wk   = (const float*)d_in[4];
    const float* Wv   = (const float*)d_in[5];
    const float* Wo   = (const float*)d_in[6];
    const float* bo   = (const float*)d_in[7];
    const float* ln1g = (const float*)d_in[8];
    const float* ln1b = (const float*)d_in[9];
    const float* W1   = (const float*)d_in[10];
    const float* b1   = (const float*)d_in[11];
    const float* W2   = (const float*)d_in[12];
    const float* b2   = (const float*)d_in[13];
    const float* ln2g = (const float*)d_in[14];
    const float* ln2b = (const float*)d_in[15];

    const int N = in_sizes[0] / 128;
    const int E = in_sizes[1];
    const int NB = (N + BSIZE - 1) >> BSHIFT;

    // ---- workspace layout ----
    unsigned short* Qh = (unsigned short*)d_ws;          // N*128 f16 (Q), bf16 h_attn after agg
    unsigned char*  KVc = (unsigned char*)(Qh + (size_t)N * 128);  // N*256 B: K fp8 | V fp8
    __hip_bfloat16* Xh = (__hip_bfloat16*)(KVc + (size_t)N * KVROW);  // N*128 bf16 (LN1 out)
    __hip_bfloat16* Wt = (__hip_bfloat16*)(Xh + (size_t)N * 128);
    __hip_bfloat16* Wqt = Wt;
    __hip_bfloat16* Wkt = Wqt + 16384;
    __hip_bfloat16* Wvt = Wkt + 16384;
    __hip_bfloat16* Wot = Wvt + 16384;
    __hip_bfloat16* W1t = Wot + 16384;        // [256][128]
    __hip_bfloat16* W2t = W1t + 32768;        // [128][256]
    int* ib       = (int*)(W2t + 32768);
    int* bCnt     = ib;                       // 256
    int* bBase    = ib + 256;                 // 257
    int* gCur     = ib + 514;                 // 256
    int* rowStart = ib + 770;                 // N+1
    int* esrc     = ib + 770 + N + 2;         // E
    uint2* P      = (uint2*)Xh;               // E pairs overlay Xh (dead during sort;
                                              //   Xh written only by LN1, after sort+agg)
    __hip_bfloat16* Th = (__hip_bfloat16*)Qh; // N*256 bf16 overlay on Qh+KVc (exactly
                                              //   N*512 B; both dead after LN1 consumes Qh)

    const dim3 blk(256);
    const int  nb    = (N + 63) / 64;
    const int  chunk = (E + 255) / 256;

    // ---- weight cast+transpose (+ bCnt zero) ----
    WArgs wa;
    wa.src[0] = Wq; wa.src[1] = Wk; wa.src[2] = Wv; wa.src[3] = Wo; wa.src[4] = W1; wa.src[5] = W2;
    wa.dst[0] = Wqt; wa.dst[1] = Wkt; wa.dst[2] = Wvt; wa.dst[3] = Wot; wa.dst[4] = W1t; wa.dst[5] = W2t;
    wa.R[0] = wa.R[1] = wa.R[2] = wa.R[3] = 128; wa.R[4] = 128; wa.R[5] = 256;
    wa.C[0] = wa.C[1] = wa.C[2] = wa.C[3] = 128; wa.C[4] = 256; wa.C[5] = 128;
    cast_w<<<dim3(128, 6), blk, 0, stream>>>(wa, bCnt);

    // ---- fused QKV (h read once) ----
    qkv_fused<<<dim3(nb), blk, 0, stream>>>(h, Wqt, Wkt, Wvt, Qh, KVc, N);

    // ---- bucketed sort of edges by dst ----
    bucket_hist<<<dim3(256), blk, 0, stream>>>(dst, bCnt, E, chunk, NB);
    bucket_scan<<<dim3(1), blk, 0, stream>>>(bCnt, bBase, gCur, rowStart, N, E, NB);
    partition_kernel<<<dim3(256), blk, 0, stream>>>(src, dst, gCur, P, E, chunk, NB);
    bucket_scatter<<<dim3(NB), blk, 0, stream>>>(P, bBase, rowStart, esrc, N);

    // ---- aggregate (reads f16 Q + fp8 K/V, writes bf16 h_attn into Qh) ----
    aggregate_kernel<<<dim3((N + 3) / 4), blk, 0, stream>>>(Qh, KVc, esrc, rowStart, N);

    // ---- X = LN1(h + h_attn@Wo + bo) -> bf16 Xh only ----
    gemm_mfma<128,1,false,true,true,true,false><<<dim3(nb), blk, 0, stream>>>(
        (const __hip_bfloat16*)Qh, 128, Wot, 128, bo, h, ln1g, ln1b,
        nullptr, Xh, 128, N);

    // ---- T = relu(X@W1 + b1) -> bf16 (both column halves in one block) ----
    gemm_mfma<128,2,true,false,false,true,false><<<dim3(nb), blk, 0, stream>>>(
        Xh, 128, W1t, 128, b1, nullptr, nullptr, nullptr,
        nullptr, Th, 256, N);

    // ---- out = LN2(X(bf16) + T@W2 + b2) -> fp32 ----
    gemm_mfma<256,1,false,true,true,true,true><<<dim3(nb), blk, 0, stream>>>(
        Th, 256, W2t, 256, b2, Xh, ln2g, ln2b,
        (float*)d_out, nullptr, 128, N);
}